// Round 10
// baseline (316.930 us; speedup 1.0000x reference)
//
#include <hip/hip_runtime.h>
#include <hip/hip_bf16.h>

#define BATCH 32768
#define NELEM 65536   // 2 * BATCH
#define FSTRIDE 584   // feat row stride (578 cols + 6 zeroed pad cols)

typedef unsigned short u16;
typedef unsigned int u32;
typedef __attribute__((ext_vector_type(8))) short bf16x8;
typedef __attribute__((ext_vector_type(4))) float f32x4;

__device__ __forceinline__ float bf2f(u16 u) {
    union { u32 u; float f; } c; c.u = ((u32)u) << 16; return c.f;
}
__device__ __forceinline__ u16 f2bf(float f) {
    union { float f; u32 u; } c; c.f = f;
    u32 x = c.u;
    u32 r = (x + 0x7fffu + ((x >> 16) & 1u)) >> 16;  // RNE
    return (u16)r;
}

// ---------------- K0: weight prep ---------------------------------------
// pwT: [64][608]; K-order kk = p*64+oc; kk=576/577 carried; kk>=578 zero.
// w2r: [oc32][k=tap*16+ic]; w3r: [oc64][k=tap*32+ic]
// h2hi/h2lo: [128][128] split-bf16 h2_w
// h1hi/h1lo: [128][160] split-bf16 zero-padded h1_w (written; h1 path
//            currently uses fp32 k6 — k6-mfma is condemned by bisection)
__global__ __launch_bounds__(256) void k0_prep(const float* __restrict__ pw,
        const float* __restrict__ w2, const float* __restrict__ w3,
        const float* __restrict__ h2w, const float* __restrict__ h1w,
        u16* __restrict__ pwT, u16* __restrict__ w2r, u16* __restrict__ w3r,
        u16* __restrict__ h2hi, u16* __restrict__ h2lo,
        u16* __restrict__ h1hi, u16* __restrict__ h1lo) {
    int idx = blockIdx.x * 256 + threadIdx.x;
    if (idx < 38912) {
        int j = idx / 608, kk = idx - j * 608;
        float v = 0.f;
        if (kk < 576) {
            int p = kk >> 6, oc = kk & 63;
            v = pw[j * 578 + oc * 9 + p];
        } else if (kk < 578) {
            v = pw[j * 578 + kk];
        }
        pwT[idx] = f2bf(v);
    } else if (idx < 40960) {
        int i = idx - 38912;
        int oc = i >> 6, rem = i & 63, tap = rem >> 4, ic = rem & 15;
        w2r[i] = f2bf(w2[oc * 64 + ic * 4 + tap]);
    } else if (idx < 49152) {
        int i = idx - 40960;
        int oc = i >> 7, rem = i & 127, tap = rem >> 5, ic = rem & 31;
        w3r[i] = f2bf(w3[oc * 128 + ic * 4 + tap]);
    } else if (idx < 65536) {
        int i = idx - 49152;
        float v = h2w[i];
        u16 hi = f2bf(v);
        h2hi[i] = hi;
        h2lo[i] = f2bf(v - bf2f(hi));
    } else if (idx < 86016) {
        int i = idx - 65536;
        int j = i / 160, k = i - j * 160;
        float v = (k < 132) ? h1w[j * 132 + k] : 0.f;
        u16 hi = f2bf(v);
        h1hi[i] = hi;
        h1lo[i] = f2bf(v - bf2f(hi));
    }
}

// ---------------- K1: conv1 (pad1,k2) + relu + maxpool2 -> bf16 --------
// Block = 16 elems staged in LDS. 16 thr/elem: thread = pooled pos,
// computes its 2x2 conv quad in-thread (identical fp32 math to the
// R3-validated kernel) -> no cross-lane ops.
__global__ __launch_bounds__(256) void k1_conv1(const int* __restrict__ frame,
        const float* __restrict__ w1, const float* __restrict__ b1,
        u16* __restrict__ pooled1b) {
    __shared__ float fr[16 * 148];
    int t = threadIdx.x;
    int e0 = blockIdx.x * 16;
    #pragma unroll
    for (int i = 0; i < 10; ++i) {
        int off = i * 256 + t;
        if (off < 2352) {
            int le = off / 147, r = off - le * 147;
            fr[le * 148 + r] = (float)frame[e0 * 147 + off];
        }
    }
    __syncthreads();
    int le = t >> 4, pos = t & 15;
    int py = pos >> 2, px = pos & 3;
    const float* fb = fr + le * 148;
    float patch[3][3][3];  // [c][dy][dx]
    int iy0 = 2 * py - 1, ix0 = 2 * px - 1;
    #pragma unroll
    for (int dy = 0; dy < 3; ++dy) {
        int iy = iy0 + dy;
        #pragma unroll
        for (int dx = 0; dx < 3; ++dx) {
            int ix = ix0 + dx;
            bool ok = (iy >= 0 && iy < 7 && ix >= 0 && ix < 7);
            int base = (iy * 7 + ix) * 3;
            #pragma unroll
            for (int c = 0; c < 3; ++c)
                patch[c][dy][dx] = ok ? fb[base + c] : 0.f;
        }
    }
    union { u16 s[16]; uint4 q[2]; } ob;
    #pragma unroll
    for (int oc = 0; oc < 16; ++oc) {
        float bias = b1[oc];
        float m = 0.0f;  // post-relu values >= 0
        #pragma unroll
        for (int sy = 0; sy < 2; ++sy)
        #pragma unroll
        for (int sx = 0; sx < 2; ++sx) {
            float acc = bias;
            #pragma unroll
            for (int ic = 0; ic < 3; ++ic)
            #pragma unroll
            for (int ky = 0; ky < 2; ++ky)
            #pragma unroll
            for (int kx = 0; kx < 2; ++kx)
                acc += patch[ic][sy + ky][sx + kx] * w1[oc * 12 + ic * 4 + ky * 2 + kx];
            acc = fmaxf(acc, 0.0f);
            m = fmaxf(m, acc);
        }
        ob.s[oc] = f2bf(m);
    }
    uint4* outp = (uint4*)(pooled1b + (e0 + le) * 256 + pos * 16);
    outp[0] = ob.q[0];
    outp[1] = ob.q[1];
}

// ---------------- K2: conv2+relu+maxpool fused via MFMA, LDS-free ------
#define K2_WAVES 4096
__global__ __launch_bounds__(256) void k2_conv2_mfma(const u16* __restrict__ pooled1b,
        const u16* __restrict__ w2r, const float* __restrict__ b2,
        u16* __restrict__ pooled2) {
    int t = threadIdx.x;
    int l = t & 63;
    int col = l & 15;
    int kg = l >> 4;
    int wv = (blockIdx.x * 256 + t) >> 6;

    bf16x8 bfrag[2][2];
    #pragma unroll
    for (int s = 0; s < 2; ++s)
        #pragma unroll
        for (int nt = 0; nt < 2; ++nt)
            bfrag[s][nt] = *(const bf16x8*)(w2r + (nt * 16 + col) * 64 + s * 32 + kg * 8);
    float bias[2] = { b2[col], b2[16 + col] };

    int oy = col >> 2, ox = col & 3;
    int aoff[2]; bool aok[2];
    #pragma unroll
    for (int s = 0; s < 2; ++s) {
        int tap = 2 * s + (kg >> 1);
        int ky = tap >> 1, kx = tap & 1;
        int iy = oy - 1 + ky, ix = ox - 1 + kx;
        aok[s] = (iy >= 0 && ix >= 0);
        aoff[s] = (iy * 4 + ix) * 16 + (kg & 1) * 8;
    }

    for (int e = wv; e < NELEM; e += K2_WAVES) {
        const u16* pbase = pooled1b + e * 256;
        bf16x8 a0 = {0,0,0,0,0,0,0,0}, a1 = {0,0,0,0,0,0,0,0};
        if (aok[0]) a0 = *(const bf16x8*)(pbase + aoff[0]);
        if (aok[1]) a1 = *(const bf16x8*)(pbase + aoff[1]);
        f32x4 acc0 = {0.f,0.f,0.f,0.f}, acc1 = {0.f,0.f,0.f,0.f};
        acc0 = __builtin_amdgcn_mfma_f32_16x16x32_bf16(a0, bfrag[0][0], acc0, 0, 0, 0);
        acc1 = __builtin_amdgcn_mfma_f32_16x16x32_bf16(a0, bfrag[0][1], acc1, 0, 0, 0);
        acc0 = __builtin_amdgcn_mfma_f32_16x16x32_bf16(a1, bfrag[1][0], acc0, 0, 0, 0);
        acc1 = __builtin_amdgcn_mfma_f32_16x16x32_bf16(a1, bfrag[1][1], acc1, 0, 0, 0);
        #pragma unroll
        for (int nt = 0; nt < 2; ++nt) {
            f32x4 acc = nt ? acc1 : acc0;
            float b = bias[nt];
            float m0 = fmaxf(fmaxf(acc[0] + b, 0.f), fmaxf(acc[1] + b, 0.f));
            float m1 = fmaxf(fmaxf(acc[2] + b, 0.f), fmaxf(acc[3] + b, 0.f));
            float p0 = fmaxf(m0, __shfl_xor(m0, 16, 64));
            float p1 = fmaxf(m1, __shfl_xor(m1, 16, 64));
            if ((kg & 1) == 0) {
                int q = (kg >> 1) * 2;
                u16* op = pooled2 + e * 128 + nt * 16 + col;
                op[q * 32]       = f2bf(p0);
                op[(q + 1) * 32] = f2bf(p1);
            }
        }
    }
}

// ---------------- K3: conv3+relu via MFMA, LDS-free --------------------
// feat layout: feat[elem][p*64 + oc] (coalesced; pwT matches K-order).
#define K3_WAVES 4096
__global__ __launch_bounds__(256) void k3_conv3_mfma(const u16* __restrict__ pooled2,
        const u16* __restrict__ w3r, const float* __restrict__ b3,
        u16* __restrict__ feat) {
    int t = threadIdx.x;
    int l = t & 63;
    int col = l & 15;
    int kg = l >> 4;
    int wv = (blockIdx.x * 256 + t) >> 6;
    const int NTILE = (NELEM * 9) / 16;  // 36864

    bf16x8 bfrag[4][4];
    #pragma unroll
    for (int s = 0; s < 4; ++s)
        #pragma unroll
        for (int nt = 0; nt < 4; ++nt)
            bfrag[s][nt] = *(const bf16x8*)(w3r + (nt * 16 + col) * 128 + s * 32 + kg * 8);
    float bias[4];
    #pragma unroll
    for (int nt = 0; nt < 4; ++nt) bias[nt] = b3[nt * 16 + col];

    for (int mt = wv; mt < NTILE; mt += K3_WAVES) {
        int m0 = mt * 16;
        int m = m0 + col;
        u32 elem = (u32)(((unsigned long long)(u32)m * 954437177ull) >> 33); // m/9
        int p = m - (int)elem * 9;
        int oy = (p * 86) >> 8;
        int ox = p - 3 * oy;
        const u16* pbase = pooled2 + (size_t)elem * 128 + kg * 8;
        f32x4 acc[4];
        #pragma unroll
        for (int nt = 0; nt < 4; ++nt) {
            acc[nt][0] = 0.f; acc[nt][1] = 0.f; acc[nt][2] = 0.f; acc[nt][3] = 0.f;
        }
        #pragma unroll
        for (int s = 0; s < 4; ++s) {
            int ky = s >> 1, kx = s & 1;
            int iy = oy - 1 + ky, ix = ox - 1 + kx;
            bf16x8 a = {0,0,0,0,0,0,0,0};
            if (iy >= 0 && iy <= 1 && ix >= 0 && ix <= 1)
                a = *(const bf16x8*)(pbase + (iy * 2 + ix) * 32);
            #pragma unroll
            for (int nt = 0; nt < 4; ++nt)
                acc[nt] = __builtin_amdgcn_mfma_f32_16x16x32_bf16(a, bfrag[s][nt], acc[nt], 0, 0, 0);
        }
        #pragma unroll
        for (int r = 0; r < 4; ++r) {
            int mr = m0 + kg * 4 + r;
            u32 er = (u32)(((unsigned long long)(u32)mr * 954437177ull) >> 33);
            int pr = mr - (int)er * 9;
            u16* fb = feat + (size_t)er * FSTRIDE + pr * 64;
            #pragma unroll
            for (int nt = 0; nt < 4; ++nt)
                fb[nt * 16 + col] = f2bf(fmaxf(acc[nt][r] + bias[nt], 0.f));
        }
    }
}

// ---------------- K3b: feat tail cols 576..583 -------------------------
__global__ __launch_bounds__(256) void k3_tail(const int* __restrict__ ccol,
        const int* __restrict__ cobj, u16* __restrict__ feat) {
    int e = blockIdx.x * 256 + threadIdx.x;
    union { u16 s[8]; uint4 q; } b;
    b.s[0] = f2bf((float)ccol[e]);
    b.s[1] = f2bf((float)cobj[e]);
    #pragma unroll
    for (int i = 2; i < 8; ++i) b.s[i] = 0;
    *(uint4*)(feat + (size_t)e * FSTRIDE + 576) = b.q;
}

// ---------------- K4: proj via MFMA, LDS-free -> emb fp32 --------------
__global__ __launch_bounds__(256) void k4_proj_mfma(const u16* __restrict__ feat,
        const u16* __restrict__ pwT, const float* __restrict__ pb,
        float* __restrict__ emb) {
    int t = threadIdx.x;
    int l = t & 63;
    int w = t >> 6;
    int m0 = blockIdx.x * 64 + w * 16;
    int col = l & 15;
    int kg = l >> 4;
    const u16* arow = feat + (size_t)(m0 + col) * FSTRIDE + kg * 8;
    const u16* brow = pwT + col * 608 + kg * 8;

    f32x4 acc[4];
    #pragma unroll
    for (int i = 0; i < 4; ++i) {
        acc[i][0] = 0.f; acc[i][1] = 0.f; acc[i][2] = 0.f; acc[i][3] = 0.f;
    }

    #pragma unroll 4
    for (int k0 = 0; k0 < 608; k0 += 32) {
        bf16x8 a;
        if (k0 + kg * 8 < 584) {
            a = *(const bf16x8*)(arow + k0);
        } else {
            #pragma unroll
            for (int j = 0; j < 8; ++j) a[j] = 0;
        }
        bf16x8 b0 = *(const bf16x8*)(brow + k0);
        bf16x8 b1 = *(const bf16x8*)(brow + 16 * 608 + k0);
        bf16x8 b2 = *(const bf16x8*)(brow + 32 * 608 + k0);
        bf16x8 b3 = *(const bf16x8*)(brow + 48 * 608 + k0);
        acc[0] = __builtin_amdgcn_mfma_f32_16x16x32_bf16(a, b0, acc[0], 0, 0, 0);
        acc[1] = __builtin_amdgcn_mfma_f32_16x16x32_bf16(a, b1, acc[1], 0, 0, 0);
        acc[2] = __builtin_amdgcn_mfma_f32_16x16x32_bf16(a, b2, acc[2], 0, 0, 0);
        acc[3] = __builtin_amdgcn_mfma_f32_16x16x32_bf16(a, b3, acc[3], 0, 0, 0);
    }

    #pragma unroll
    for (int nt = 0; nt < 4; ++nt) {
        float pbv = pb[nt * 16 + col];
        #pragma unroll
        for (int r = 0; r < 4; ++r) {
            int row = m0 + kg * 4 + r;
            emb[row * 64 + nt * 16 + col] = fmaxf(acc[nt][r] + pbv, 0.f);
        }
    }
}

// ---------------- K5: dir_pos deltas -> extras[b][4] fp32 ---------------
__global__ __launch_bounds__(256) void k5_extras(const int* __restrict__ frame,
        float* __restrict__ extras) {
    int b = blockIdx.x * 256 + threadIdx.x;
    int d[2]; float posy[2], posx[2];
    for (int f = 0; f < 2; ++f) {
        const int* fb = frame + (size_t)(f * BATCH + b) * 147;
        int idx = 49;
        for (int cell = 0; cell < 49; ++cell) {
            int v = fb[cell * 3];
            if (idx == 49 && v == 10) idx = cell;
        }
        if (idx < 49) {
            d[f] = fb[idx * 3 + 2] & 3;
            posy[f] = (float)(idx / 7) / 6.0f;
            posx[f] = (float)(idx % 7) / 6.0f;
        } else {
            d[f] = 0; posy[f] = 0.5f; posx[f] = 0.5f;
        }
    }
    int delta = (d[1] - d[0] + 4) & 3;
    const float ANG = (float)(2.0 * 3.14159 / 4.0);
    float angle = (float)delta * ANG;
    float4 o;
    o.x = sinf(angle);
    o.y = cosf(angle);
    o.z = posy[1] - posy[0];
    o.w = posx[1] - posx[0];
    *(float4*)(extras + b * 4) = o;
}

// ---------------- K6: h1 GEMM (gathered A, K=132) + bias + LN + relu ----
// R8-validated fp32 LDS version (k6-mfma condemned by R9 bisection).
__global__ __launch_bounds__(128) void k6_h1(
        const float* __restrict__ emb, const float* __restrict__ extras,
        const float* __restrict__ w, const float* __restrict__ bias,
        const float* __restrict__ lng, const float* __restrict__ lnb,
        float* __restrict__ out) {
    __shared__ float As[64 * 133];
    __shared__ float Bs[32 * 129];
    __shared__ float mu_s[64], rs_s[64];
    int t = threadIdx.x;
    int b0 = blockIdx.x * 64;
    {
        int r = t >> 1, half = t & 1;
        int gb = b0 + r;
        for (int kk = 0; kk < 66; ++kk) {
            int k = half * 66 + kk;
            float v;
            if (k < 64)       v = emb[gb * 64 + k];
            else if (k < 128) v = emb[(BATCH + gb) * 64 + (k - 64)];
            else              v = extras[gb * 4 + (k - 128)];
            As[r * 133 + k] = v;
        }
    }
    int tm = t >> 4, tn = t & 15;
    float acc[8][8];
    #pragma unroll
    for (int i = 0; i < 8; ++i)
        #pragma unroll
        for (int j = 0; j < 8; ++j) acc[i][j] = 0.f;

    for (int k0 = 0; k0 < 132; k0 += 32) {
        int kl = 132 - k0; if (kl > 32) kl = 32;
        __syncthreads();
        for (int i = 0; i < 32; ++i) {
            int idx = i * 128 + t;
            int j = idx >> 5, kk = idx & 31;
            Bs[kk * 129 + j] = (kk < kl) ? w[j * 132 + k0 + kk] : 0.f;
        }
        __syncthreads();
        for (int kk = 0; kk < kl; ++kk) {
            float a[8], b[8];
            #pragma unroll
            for (int i = 0; i < 8; ++i) a[i] = As[(tm * 8 + i) * 133 + k0 + kk];
            #pragma unroll
            for (int j = 0; j < 8; ++j) b[j] = Bs[kk * 129 + tn + 16 * j];
            #pragma unroll
            for (int i = 0; i < 8; ++i)
                #pragma unroll
                for (int j = 0; j < 8; ++j)
                    acc[i][j] += a[i] * b[j];
        }
    }
    __syncthreads();
    float* h = As;
    #pragma unroll
    for (int i = 0; i < 8; ++i)
        #pragma unroll
        for (int j = 0; j < 8; ++j) {
            int jj = tn + 16 * j;
            h[(tm * 8 + i) * 129 + jj] = acc[i][j] + bias[jj];
        }
    __syncthreads();
    if (t < 64) {
        float s = 0.f;
        for (int k = 0; k < 128; ++k) s += h[t * 129 + k];
        float mu = s * (1.0f / 128.0f);
        float vs = 0.f;
        for (int k = 0; k < 128; ++k) { float d = h[t * 129 + k] - mu; vs += d * d; }
        mu_s[t] = mu;
        rs_s[t] = rsqrtf(vs * (1.0f / 128.0f) + 1e-5f);
    }
    __syncthreads();
    for (int i = 0; i < 64; ++i) {
        int o = i * 128 + t;
        int r = o >> 7, j = o & 127;
        float v = (h[r * 129 + j] - mu_s[r]) * rs_s[r] * lng[j] + lnb[j];
        out[(b0 + r) * 128 + j] = fmaxf(v, 0.f);
    }
}

__device__ __forceinline__ void split8(const float* __restrict__ x,
                                       bf16x8& hi, bf16x8& lo) {
    #pragma unroll
    for (int j = 0; j < 8; ++j) {
        u16 h = f2bf(x[j]);
        hi[j] = (short)h;
        lo[j] = (short)f2bf(x[j] - bf2f(h));
    }
}

// ---------------- K7: h2 via split-bf16 MFMA (fp32 in/out) -------------
// Validated at R8 (absmax unchanged).
__global__ __launch_bounds__(256) void k7_h2_mfma(const float* __restrict__ in,
        const u16* __restrict__ whi, const u16* __restrict__ wlo,
        const float* __restrict__ bias, float* __restrict__ out) {
    int t = threadIdx.x;
    int l = t & 63;
    int col = l & 15;
    int kg = l >> 4;
    int m0 = blockIdx.x * 64 + (t >> 6) * 16;
    const float* arow = in + (size_t)(m0 + col) * 128 + kg * 8;
    const u16* bh = whi + col * 128 + kg * 8;
    const u16* bl = wlo + col * 128 + kg * 8;

    f32x4 acc[8];
    #pragma unroll
    for (int nt = 0; nt < 8; ++nt) {
        acc[nt][0] = 0.f; acc[nt][1] = 0.f; acc[nt][2] = 0.f; acc[nt][3] = 0.f;
    }
    #pragma unroll
    for (int s = 0; s < 4; ++s) {
        float x[8];
        #pragma unroll
        for (int j = 0; j < 8; ++j) x[j] = arow[s * 32 + j];
        bf16x8 ahi, alo;
        split8(x, ahi, alo);
        #pragma unroll
        for (int nt = 0; nt < 8; ++nt) {
            bf16x8 bhiF = *(const bf16x8*)(bh + nt * 2048 + s * 32);
            bf16x8 bloF = *(const bf16x8*)(bl + nt * 2048 + s * 32);
            acc[nt] = __builtin_amdgcn_mfma_f32_16x16x32_bf16(ahi, bhiF, acc[nt], 0, 0, 0);
            acc[nt] = __builtin_amdgcn_mfma_f32_16x16x32_bf16(alo, bhiF, acc[nt], 0, 0, 0);
            acc[nt] = __builtin_amdgcn_mfma_f32_16x16x32_bf16(ahi, bloF, acc[nt], 0, 0, 0);
        }
    }
    #pragma unroll
    for (int nt = 0; nt < 8; ++nt) {
        float bv = bias[nt * 16 + col];
        #pragma unroll
        for (int r = 0; r < 4; ++r) {
            int m = m0 + kg * 4 + r;
            out[m * 128 + nt * 16 + col] = fmaxf(acc[nt][r] + bv, 0.f);
        }
    }
}

// ---------------- K8: h3 [32768x128]@[128->7], thread = row, fp32 ------
__global__ __launch_bounds__(256) void k8_h3(const float* __restrict__ in,
        const float* __restrict__ w, const float* __restrict__ bias,
        float* __restrict__ out) {
    int r = blockIdx.x * 256 + threadIdx.x;
    float acc[7];
    #pragma unroll
    for (int j = 0; j < 7; ++j) acc[j] = bias[j];
    const float* row = in + (size_t)r * 128;
    #pragma unroll 4
    for (int c = 0; c < 32; ++c) {
        float4 v = *(const float4*)(row + c * 4);
        #pragma unroll
        for (int j = 0; j < 7; ++j) {
            acc[j] += v.x * w[j * 128 + c * 4 + 0];
            acc[j] += v.y * w[j * 128 + c * 4 + 1];
            acc[j] += v.z * w[j * 128 + c * 4 + 2];
            acc[j] += v.w * w[j * 128 + c * 4 + 3];
        }
    }
    #pragma unroll
    for (int j = 0; j < 7; ++j) out[r * 7 + j] = acc[j];
}

extern "C" void kernel_launch(void* const* d_in, const int* in_sizes, int n_in,
                              void* d_out, int out_size, void* d_ws, size_t ws_size,
                              hipStream_t stream) {
    const int*   frame = (const int*)d_in[0];
    const int*   ccol  = (const int*)d_in[1];
    const int*   cobj  = (const int*)d_in[2];
    const float* w1    = (const float*)d_in[3];
    const float* b1    = (const float*)d_in[4];
    const float* w2    = (const float*)d_in[5];
    const float* b2    = (const float*)d_in[6];
    const float* w3    = (const float*)d_in[7];
    const float* b3    = (const float*)d_in[8];
    const float* pw    = (const float*)d_in[9];
    const float* pb    = (const float*)d_in[10];
    const float* h1w   = (const float*)d_in[11];
    const float* h1b   = (const float*)d_in[12];
    const float* lng   = (const float*)d_in[13];
    const float* lnb   = (const float*)d_in[14];
    const float* h2w   = (const float*)d_in[15];
    const float* h2b   = (const float*)d_in[16];
    const float* h3w   = (const float*)d_in[17];
    const float* h3b   = (const float*)d_in[18];
    float* out = (float*)d_out;

    char* ws = (char*)d_ws;
    u16*   pooled1b = (u16*)(ws + 0);                    // 32 MB
    float* emb      = (float*)(ws + 0);                  // 16 MB (after k2)
    float* extras   = (float*)(ws + 16777216);           // 512 KB
    u16*   pooled2  = (u16*)(ws + 33554432);             // 16 MB
    float* h1out    = (float*)(ws + 33554432);           // 16 MB (after k3)
    u16*   feat     = (u16*)(ws + 50331648);             // 76.5 MB
    float* h2out    = (float*)(ws + 50331648);           // 16 MB (after k4)
    u16*   pwT      = (u16*)(ws + 132120576);            // 77824 B
    u16*   w2r      = (u16*)(ws + 132120576 + 131072);   // 4096 B
    u16*   w3r      = (u16*)(ws + 132120576 + 139264);   // 16384 B
    u16*   h2hi     = (u16*)(ws + 132120576 + 163840);   // 32768 B
    u16*   h2lo     = (u16*)(ws + 132120576 + 196608);   // 32768 B
    u16*   h1hi     = (u16*)(ws + 132120576 + 229376);   // 40960 B
    u16*   h1lo     = (u16*)(ws + 132120576 + 270336);   // 40960 B

    k0_prep<<<336, 256, 0, stream>>>(pw, w2, w3, h2w, h1w,
                                     pwT, w2r, w3r, h2hi, h2lo, h1hi, h1lo);
    k1_conv1<<<4096, 256, 0, stream>>>(frame, w1, b1, pooled1b);
    k2_conv2_mfma<<<1024, 256, 0, stream>>>(pooled1b, w2r, b2, pooled2);
    k3_conv3_mfma<<<1024, 256, 0, stream>>>(pooled2, w3r, b3, feat);
    k3_tail<<<256, 256, 0, stream>>>(ccol, cobj, feat);
    k4_proj_mfma<<<1024, 256, 0, stream>>>(feat, pwT, pb, emb);
    k5_extras<<<128, 256, 0, stream>>>(frame, extras);
    k6_h1<<<512, 128, 0, stream>>>(emb, extras, h1w, h1b, lng, lnb, h1out);
    k7_h2_mfma<<<512, 256, 0, stream>>>(h1out, h2hi, h2lo, h2b, h2out);
    k8_h3<<<128, 256, 0, stream>>>(h2out, h3w, h3b, out);
}

// Round 11
// 305.642 us; speedup vs baseline: 1.0369x; 1.0369x over previous
//
#include <hip/hip_runtime.h>
#include <hip/hip_bf16.h>

#define BATCH 32768
#define NELEM 65536   // 2 * BATCH
#define FSTRIDE 584   // feat row stride (578 cols + 6 zeroed pad cols)

typedef unsigned short u16;
typedef unsigned int u32;
typedef __attribute__((ext_vector_type(8))) short bf16x8;
typedef __attribute__((ext_vector_type(4))) float f32x4;

__device__ __forceinline__ float bf2f(u16 u) {
    union { u32 u; float f; } c; c.u = ((u32)u) << 16; return c.f;
}
__device__ __forceinline__ u16 f2bf(float f) {
    union { float f; u32 u; } c; c.f = f;
    u32 x = c.u;
    u32 r = (x + 0x7fffu + ((x >> 16) & 1u)) >> 16;  // RNE
    return (u16)r;
}

// ---------------- K0: weight prep ---------------------------------------
__global__ __launch_bounds__(256) void k0_prep(const float* __restrict__ pw,
        const float* __restrict__ w2, const float* __restrict__ w3,
        const float* __restrict__ h2w, const float* __restrict__ h1w,
        u16* __restrict__ pwT, u16* __restrict__ w2r, u16* __restrict__ w3r,
        u16* __restrict__ h2hi, u16* __restrict__ h2lo,
        u16* __restrict__ h1hi, u16* __restrict__ h1lo) {
    int idx = blockIdx.x * 256 + threadIdx.x;
    if (idx < 38912) {
        int j = idx / 608, kk = idx - j * 608;
        float v = 0.f;
        if (kk < 576) {
            int p = kk >> 6, oc = kk & 63;
            v = pw[j * 578 + oc * 9 + p];
        } else if (kk < 578) {
            v = pw[j * 578 + kk];
        }
        pwT[idx] = f2bf(v);
    } else if (idx < 40960) {
        int i = idx - 38912;
        int oc = i >> 6, rem = i & 63, tap = rem >> 4, ic = rem & 15;
        w2r[i] = f2bf(w2[oc * 64 + ic * 4 + tap]);
    } else if (idx < 49152) {
        int i = idx - 40960;
        int oc = i >> 7, rem = i & 127, tap = rem >> 5, ic = rem & 31;
        w3r[i] = f2bf(w3[oc * 128 + ic * 4 + tap]);
    } else if (idx < 65536) {
        int i = idx - 49152;
        float v = h2w[i];
        u16 hi = f2bf(v);
        h2hi[i] = hi;
        h2lo[i] = f2bf(v - bf2f(hi));
    } else if (idx < 86016) {
        int i = idx - 65536;
        int j = i / 160, k = i - j * 160;
        float v = (k < 132) ? h1w[j * 132 + k] : 0.f;
        u16 hi = f2bf(v);
        h1hi[i] = hi;
        h1lo[i] = f2bf(v - bf2f(hi));
    }
}

// ---------------- K1: conv1 (pad1,k2) + relu + maxpool2 -> bf16 --------
__global__ __launch_bounds__(256) void k1_conv1(const int* __restrict__ frame,
        const float* __restrict__ w1, const float* __restrict__ b1,
        u16* __restrict__ pooled1b) {
    __shared__ float fr[16 * 148];
    int t = threadIdx.x;
    int e0 = blockIdx.x * 16;
    #pragma unroll
    for (int i = 0; i < 10; ++i) {
        int off = i * 256 + t;
        if (off < 2352) {
            int le = off / 147, r = off - le * 147;
            fr[le * 148 + r] = (float)frame[e0 * 147 + off];
        }
    }
    __syncthreads();
    int le = t >> 4, pos = t & 15;
    int py = pos >> 2, px = pos & 3;
    const float* fb = fr + le * 148;
    float patch[3][3][3];  // [c][dy][dx]
    int iy0 = 2 * py - 1, ix0 = 2 * px - 1;
    #pragma unroll
    for (int dy = 0; dy < 3; ++dy) {
        int iy = iy0 + dy;
        #pragma unroll
        for (int dx = 0; dx < 3; ++dx) {
            int ix = ix0 + dx;
            bool ok = (iy >= 0 && iy < 7 && ix >= 0 && ix < 7);
            int base = (iy * 7 + ix) * 3;
            #pragma unroll
            for (int c = 0; c < 3; ++c)
                patch[c][dy][dx] = ok ? fb[base + c] : 0.f;
        }
    }
    union { u16 s[16]; uint4 q[2]; } ob;
    #pragma unroll
    for (int oc = 0; oc < 16; ++oc) {
        float bias = b1[oc];
        float m = 0.0f;  // post-relu values >= 0
        #pragma unroll
        for (int sy = 0; sy < 2; ++sy)
        #pragma unroll
        for (int sx = 0; sx < 2; ++sx) {
            float acc = bias;
            #pragma unroll
            for (int ic = 0; ic < 3; ++ic)
            #pragma unroll
            for (int ky = 0; ky < 2; ++ky)
            #pragma unroll
            for (int kx = 0; kx < 2; ++kx)
                acc += patch[ic][sy + ky][sx + kx] * w1[oc * 12 + ic * 4 + ky * 2 + kx];
            acc = fmaxf(acc, 0.0f);
            m = fmaxf(m, acc);
        }
        ob.s[oc] = f2bf(m);
    }
    uint4* outp = (uint4*)(pooled1b + (e0 + le) * 256 + pos * 16);
    outp[0] = ob.q[0];
    outp[1] = ob.q[1];
}

// ---------------- K2: conv2+relu+maxpool fused via MFMA, LDS-free ------
#define K2_WAVES 4096
__global__ __launch_bounds__(256) void k2_conv2_mfma(const u16* __restrict__ pooled1b,
        const u16* __restrict__ w2r, const float* __restrict__ b2,
        u16* __restrict__ pooled2) {
    int t = threadIdx.x;
    int l = t & 63;
    int col = l & 15;
    int kg = l >> 4;
    int wv = (blockIdx.x * 256 + t) >> 6;

    bf16x8 bfrag[2][2];
    #pragma unroll
    for (int s = 0; s < 2; ++s)
        #pragma unroll
        for (int nt = 0; nt < 2; ++nt)
            bfrag[s][nt] = *(const bf16x8*)(w2r + (nt * 16 + col) * 64 + s * 32 + kg * 8);
    float bias[2] = { b2[col], b2[16 + col] };

    int oy = col >> 2, ox = col & 3;
    int aoff[2]; bool aok[2];
    #pragma unroll
    for (int s = 0; s < 2; ++s) {
        int tap = 2 * s + (kg >> 1);
        int ky = tap >> 1, kx = tap & 1;
        int iy = oy - 1 + ky, ix = ox - 1 + kx;
        aok[s] = (iy >= 0 && ix >= 0);
        aoff[s] = (iy * 4 + ix) * 16 + (kg & 1) * 8;
    }

    for (int e = wv; e < NELEM; e += K2_WAVES) {
        const u16* pbase = pooled1b + e * 256;
        bf16x8 a0 = {0,0,0,0,0,0,0,0}, a1 = {0,0,0,0,0,0,0,0};
        if (aok[0]) a0 = *(const bf16x8*)(pbase + aoff[0]);
        if (aok[1]) a1 = *(const bf16x8*)(pbase + aoff[1]);
        f32x4 acc0 = {0.f,0.f,0.f,0.f}, acc1 = {0.f,0.f,0.f,0.f};
        acc0 = __builtin_amdgcn_mfma_f32_16x16x32_bf16(a0, bfrag[0][0], acc0, 0, 0, 0);
        acc1 = __builtin_amdgcn_mfma_f32_16x16x32_bf16(a0, bfrag[0][1], acc1, 0, 0, 0);
        acc0 = __builtin_amdgcn_mfma_f32_16x16x32_bf16(a1, bfrag[1][0], acc0, 0, 0, 0);
        acc1 = __builtin_amdgcn_mfma_f32_16x16x32_bf16(a1, bfrag[1][1], acc1, 0, 0, 0);
        #pragma unroll
        for (int nt = 0; nt < 2; ++nt) {
            f32x4 acc = nt ? acc1 : acc0;
            float b = bias[nt];
            float m0 = fmaxf(fmaxf(acc[0] + b, 0.f), fmaxf(acc[1] + b, 0.f));
            float m1 = fmaxf(fmaxf(acc[2] + b, 0.f), fmaxf(acc[3] + b, 0.f));
            float p0 = fmaxf(m0, __shfl_xor(m0, 16, 64));
            float p1 = fmaxf(m1, __shfl_xor(m1, 16, 64));
            if ((kg & 1) == 0) {
                int q = (kg >> 1) * 2;
                u16* op = pooled2 + e * 128 + nt * 16 + col;
                op[q * 32]       = f2bf(p0);
                op[(q + 1) * 32] = f2bf(p1);
            }
        }
    }
}

// ---------------- K3: conv3+relu via MFMA, LDS-free --------------------
#define K3_WAVES 4096
__global__ __launch_bounds__(256) void k3_conv3_mfma(const u16* __restrict__ pooled2,
        const u16* __restrict__ w3r, const float* __restrict__ b3,
        u16* __restrict__ feat) {
    int t = threadIdx.x;
    int l = t & 63;
    int col = l & 15;
    int kg = l >> 4;
    int wv = (blockIdx.x * 256 + t) >> 6;
    const int NTILE = (NELEM * 9) / 16;  // 36864

    bf16x8 bfrag[4][4];
    #pragma unroll
    for (int s = 0; s < 4; ++s)
        #pragma unroll
        for (int nt = 0; nt < 4; ++nt)
            bfrag[s][nt] = *(const bf16x8*)(w3r + (nt * 16 + col) * 128 + s * 32 + kg * 8);
    float bias[4];
    #pragma unroll
    for (int nt = 0; nt < 4; ++nt) bias[nt] = b3[nt * 16 + col];

    for (int mt = wv; mt < NTILE; mt += K3_WAVES) {
        int m0 = mt * 16;
        int m = m0 + col;
        u32 elem = (u32)(((unsigned long long)(u32)m * 954437177ull) >> 33); // m/9
        int p = m - (int)elem * 9;
        int oy = (p * 86) >> 8;
        int ox = p - 3 * oy;
        const u16* pbase = pooled2 + (size_t)elem * 128 + kg * 8;
        f32x4 acc[4];
        #pragma unroll
        for (int nt = 0; nt < 4; ++nt) {
            acc[nt][0] = 0.f; acc[nt][1] = 0.f; acc[nt][2] = 0.f; acc[nt][3] = 0.f;
        }
        #pragma unroll
        for (int s = 0; s < 4; ++s) {
            int ky = s >> 1, kx = s & 1;
            int iy = oy - 1 + ky, ix = ox - 1 + kx;
            bf16x8 a = {0,0,0,0,0,0,0,0};
            if (iy >= 0 && iy <= 1 && ix >= 0 && ix <= 1)
                a = *(const bf16x8*)(pbase + (iy * 2 + ix) * 32);
            #pragma unroll
            for (int nt = 0; nt < 4; ++nt)
                acc[nt] = __builtin_amdgcn_mfma_f32_16x16x32_bf16(a, bfrag[s][nt], acc[nt], 0, 0, 0);
        }
        #pragma unroll
        for (int r = 0; r < 4; ++r) {
            int mr = m0 + kg * 4 + r;
            u32 er = (u32)(((unsigned long long)(u32)mr * 954437177ull) >> 33);
            int pr = mr - (int)er * 9;
            u16* fb = feat + (size_t)er * FSTRIDE + pr * 64;
            #pragma unroll
            for (int nt = 0; nt < 4; ++nt)
                fb[nt * 16 + col] = f2bf(fmaxf(acc[nt][r] + bias[nt], 0.f));
        }
    }
}

// ---------------- K3b: feat tail cols 576..583 -------------------------
__global__ __launch_bounds__(256) void k3_tail(const int* __restrict__ ccol,
        const int* __restrict__ cobj, u16* __restrict__ feat) {
    int e = blockIdx.x * 256 + threadIdx.x;
    union { u16 s[8]; uint4 q; } b;
    b.s[0] = f2bf((float)ccol[e]);
    b.s[1] = f2bf((float)cobj[e]);
    #pragma unroll
    for (int i = 2; i < 8; ++i) b.s[i] = 0;
    *(uint4*)(feat + (size_t)e * FSTRIDE + 576) = b.q;
}

// ---------------- K4: proj via MFMA, LDS-free -> emb fp32 --------------
__global__ __launch_bounds__(256) void k4_proj_mfma(const u16* __restrict__ feat,
        const u16* __restrict__ pwT, const float* __restrict__ pb,
        float* __restrict__ emb) {
    int t = threadIdx.x;
    int l = t & 63;
    int w = t >> 6;
    int m0 = blockIdx.x * 64 + w * 16;
    int col = l & 15;
    int kg = l >> 4;
    const u16* arow = feat + (size_t)(m0 + col) * FSTRIDE + kg * 8;
    const u16* brow = pwT + col * 608 + kg * 8;

    f32x4 acc[4];
    #pragma unroll
    for (int i = 0; i < 4; ++i) {
        acc[i][0] = 0.f; acc[i][1] = 0.f; acc[i][2] = 0.f; acc[i][3] = 0.f;
    }

    #pragma unroll 4
    for (int k0 = 0; k0 < 608; k0 += 32) {
        bf16x8 a;
        if (k0 + kg * 8 < 584) {
            a = *(const bf16x8*)(arow + k0);
        } else {
            #pragma unroll
            for (int j = 0; j < 8; ++j) a[j] = 0;
        }
        bf16x8 b0 = *(const bf16x8*)(brow + k0);
        bf16x8 b1 = *(const bf16x8*)(brow + 16 * 608 + k0);
        bf16x8 b2 = *(const bf16x8*)(brow + 32 * 608 + k0);
        bf16x8 b3 = *(const bf16x8*)(brow + 48 * 608 + k0);
        acc[0] = __builtin_amdgcn_mfma_f32_16x16x32_bf16(a, b0, acc[0], 0, 0, 0);
        acc[1] = __builtin_amdgcn_mfma_f32_16x16x32_bf16(a, b1, acc[1], 0, 0, 0);
        acc[2] = __builtin_amdgcn_mfma_f32_16x16x32_bf16(a, b2, acc[2], 0, 0, 0);
        acc[3] = __builtin_amdgcn_mfma_f32_16x16x32_bf16(a, b3, acc[3], 0, 0, 0);
    }

    #pragma unroll
    for (int nt = 0; nt < 4; ++nt) {
        float pbv = pb[nt * 16 + col];
        #pragma unroll
        for (int r = 0; r < 4; ++r) {
            int row = m0 + kg * 4 + r;
            emb[row * 64 + nt * 16 + col] = fmaxf(acc[nt][r] + pbv, 0.f);
        }
    }
}

// ---------------- K5: dir_pos deltas -> extras[b][4] fp32 ---------------
__global__ __launch_bounds__(256) void k5_extras(const int* __restrict__ frame,
        float* __restrict__ extras) {
    int b = blockIdx.x * 256 + threadIdx.x;
    int d[2]; float posy[2], posx[2];
    for (int f = 0; f < 2; ++f) {
        const int* fb = frame + (size_t)(f * BATCH + b) * 147;
        int idx = 49;
        for (int cell = 0; cell < 49; ++cell) {
            int v = fb[cell * 3];
            if (idx == 49 && v == 10) idx = cell;
        }
        if (idx < 49) {
            d[f] = fb[idx * 3 + 2] & 3;
            posy[f] = (float)(idx / 7) / 6.0f;
            posx[f] = (float)(idx % 7) / 6.0f;
        } else {
            d[f] = 0; posy[f] = 0.5f; posx[f] = 0.5f;
        }
    }
    int delta = (d[1] - d[0] + 4) & 3;
    const float ANG = (float)(2.0 * 3.14159 / 4.0);
    float angle = (float)delta * ANG;
    float4 o;
    o.x = sinf(angle);
    o.y = cosf(angle);
    o.z = posy[1] - posy[0];
    o.w = posx[1] - posx[0];
    *(float4*)(extras + b * 4) = o;
}

// ---------------- K5b: pack comb[32768][160] fp32 ----------------------
// cols 0..63 = emb(curr), 64..127 = emb(next), 128..131 = extras, rest 0.
__global__ __launch_bounds__(256) void k5b_pack(const float* __restrict__ emb,
        const float* __restrict__ extras, float* __restrict__ comb) {
    int t = threadIdx.x;
    int b = blockIdx.x * 8 + (t >> 5);
    int q = t & 31;
    float4 v;
    if (q < 16) v = *(const float4*)(emb + (size_t)b * 64 + q * 4);
    else        v = *(const float4*)(emb + (size_t)(BATCH + b) * 64 + (q - 16) * 4);
    *(float4*)(comb + (size_t)b * 160 + q * 4) = v;
    if (t < 64) {
        int b2 = blockIdx.x * 8 + (t >> 3);
        int q2 = t & 7;
        float4 z = make_float4(0.f, 0.f, 0.f, 0.f);
        if (q2 == 0) z = *(const float4*)(extras + (size_t)b2 * 4);
        *(float4*)(comb + (size_t)b2 * 160 + 128 + q2 * 4) = z;
    }
}

__device__ __forceinline__ void split8(const float* __restrict__ x,
                                       bf16x8& hi, bf16x8& lo) {
    #pragma unroll
    for (int j = 0; j < 8; ++j) {
        u16 h = f2bf(x[j]);
        hi[j] = (short)h;
        lo[j] = (short)f2bf(x[j] - bf2f(h));
    }
}

// ---------------- K6a: h1 GEMM via split-bf16 MFMA (no LN) -------------
// Structurally identical to validated k7_h2_mfma; only K=160 (5 steps).
// Writes pre-LN h + bias, fp32, no relu.
__global__ __launch_bounds__(256) void k6_h1_gemm(const float* __restrict__ in,
        const u16* __restrict__ whi, const u16* __restrict__ wlo,
        const float* __restrict__ bias, float* __restrict__ out) {
    int t = threadIdx.x;
    int l = t & 63;
    int col = l & 15;
    int kg = l >> 4;
    int m0 = blockIdx.x * 64 + (t >> 6) * 16;
    const float* arow = in + (size_t)(m0 + col) * 160 + kg * 8;
    const u16* bh = whi + col * 160 + kg * 8;
    const u16* bl = wlo + col * 160 + kg * 8;

    f32x4 acc[8];
    #pragma unroll
    for (int nt = 0; nt < 8; ++nt) {
        acc[nt][0] = 0.f; acc[nt][1] = 0.f; acc[nt][2] = 0.f; acc[nt][3] = 0.f;
    }
    #pragma unroll
    for (int s = 0; s < 5; ++s) {
        float x[8];
        #pragma unroll
        for (int j = 0; j < 8; ++j) x[j] = arow[s * 32 + j];
        bf16x8 ahi, alo;
        split8(x, ahi, alo);
        #pragma unroll
        for (int nt = 0; nt < 8; ++nt) {
            bf16x8 bhiF = *(const bf16x8*)(bh + nt * 2560 + s * 32);
            bf16x8 bloF = *(const bf16x8*)(bl + nt * 2560 + s * 32);
            acc[nt] = __builtin_amdgcn_mfma_f32_16x16x32_bf16(ahi, bhiF, acc[nt], 0, 0, 0);
            acc[nt] = __builtin_amdgcn_mfma_f32_16x16x32_bf16(alo, bhiF, acc[nt], 0, 0, 0);
            acc[nt] = __builtin_amdgcn_mfma_f32_16x16x32_bf16(ahi, bloF, acc[nt], 0, 0, 0);
        }
    }
    #pragma unroll
    for (int nt = 0; nt < 8; ++nt) {
        float bv = bias[nt * 16 + col];
        #pragma unroll
        for (int r = 0; r < 4; ++r) {
            int m = m0 + kg * 4 + r;
            out[m * 128 + nt * 16 + col] = acc[nt][r] + bv;
        }
    }
}

// ---------------- K6b: LayerNorm + relu, wave per row ------------------
__global__ __launch_bounds__(256) void k6_ln(const float* __restrict__ h,
        const float* __restrict__ lng, const float* __restrict__ lnb,
        float* __restrict__ out) {
    int w = (blockIdx.x * 256 + threadIdx.x) >> 6;
    int l = threadIdx.x & 63;
    const float* row = h + (size_t)w * 128 + l * 2;
    float2 v = *(const float2*)row;
    float s = v.x + v.y;
    s += __shfl_xor(s, 1, 64);
    s += __shfl_xor(s, 2, 64);
    s += __shfl_xor(s, 4, 64);
    s += __shfl_xor(s, 8, 64);
    s += __shfl_xor(s, 16, 64);
    s += __shfl_xor(s, 32, 64);
    float mu = s * (1.0f / 128.0f);
    float d0 = v.x - mu, d1 = v.y - mu;
    float vs = d0 * d0 + d1 * d1;
    vs += __shfl_xor(vs, 1, 64);
    vs += __shfl_xor(vs, 2, 64);
    vs += __shfl_xor(vs, 4, 64);
    vs += __shfl_xor(vs, 8, 64);
    vs += __shfl_xor(vs, 16, 64);
    vs += __shfl_xor(vs, 32, 64);
    float rs = rsqrtf(vs * (1.0f / 128.0f) + 1e-5f);
    float2 o;
    o.x = fmaxf(d0 * rs * lng[l * 2]     + lnb[l * 2],     0.f);
    o.y = fmaxf(d1 * rs * lng[l * 2 + 1] + lnb[l * 2 + 1], 0.f);
    *(float2*)(out + (size_t)w * 128 + l * 2) = o;
}

// ---------------- K7: h2 via split-bf16 MFMA (fp32 in/out) -------------
__global__ __launch_bounds__(256) void k7_h2_mfma(const float* __restrict__ in,
        const u16* __restrict__ whi, const u16* __restrict__ wlo,
        const float* __restrict__ bias, float* __restrict__ out) {
    int t = threadIdx.x;
    int l = t & 63;
    int col = l & 15;
    int kg = l >> 4;
    int m0 = blockIdx.x * 64 + (t >> 6) * 16;
    const float* arow = in + (size_t)(m0 + col) * 128 + kg * 8;
    const u16* bh = whi + col * 128 + kg * 8;
    const u16* bl = wlo + col * 128 + kg * 8;

    f32x4 acc[8];
    #pragma unroll
    for (int nt = 0; nt < 8; ++nt) {
        acc[nt][0] = 0.f; acc[nt][1] = 0.f; acc[nt][2] = 0.f; acc[nt][3] = 0.f;
    }
    #pragma unroll
    for (int s = 0; s < 4; ++s) {
        float x[8];
        #pragma unroll
        for (int j = 0; j < 8; ++j) x[j] = arow[s * 32 + j];
        bf16x8 ahi, alo;
        split8(x, ahi, alo);
        #pragma unroll
        for (int nt = 0; nt < 8; ++nt) {
            bf16x8 bhiF = *(const bf16x8*)(bh + nt * 2048 + s * 32);
            bf16x8 bloF = *(const bf16x8*)(bl + nt * 2048 + s * 32);
            acc[nt] = __builtin_amdgcn_mfma_f32_16x16x32_bf16(ahi, bhiF, acc[nt], 0, 0, 0);
            acc[nt] = __builtin_amdgcn_mfma_f32_16x16x32_bf16(alo, bhiF, acc[nt], 0, 0, 0);
            acc[nt] = __builtin_amdgcn_mfma_f32_16x16x32_bf16(ahi, bloF, acc[nt], 0, 0, 0);
        }
    }
    #pragma unroll
    for (int nt = 0; nt < 8; ++nt) {
        float bv = bias[nt * 16 + col];
        #pragma unroll
        for (int r = 0; r < 4; ++r) {
            int m = m0 + kg * 4 + r;
            out[m * 128 + nt * 16 + col] = fmaxf(acc[nt][r] + bv, 0.f);
        }
    }
}

// ---------------- K8: h3 [32768x128]@[128->7], thread = row, fp32 ------
__global__ __launch_bounds__(256) void k8_h3(const float* __restrict__ in,
        const float* __restrict__ w, const float* __restrict__ bias,
        float* __restrict__ out) {
    int r = blockIdx.x * 256 + threadIdx.x;
    float acc[7];
    #pragma unroll
    for (int j = 0; j < 7; ++j) acc[j] = bias[j];
    const float* row = in + (size_t)r * 128;
    #pragma unroll 4
    for (int c = 0; c < 32; ++c) {
        float4 v = *(const float4*)(row + c * 4);
        #pragma unroll
        for (int j = 0; j < 7; ++j) {
            acc[j] += v.x * w[j * 128 + c * 4 + 0];
            acc[j] += v.y * w[j * 128 + c * 4 + 1];
            acc[j] += v.z * w[j * 128 + c * 4 + 2];
            acc[j] += v.w * w[j * 128 + c * 4 + 3];
        }
    }
    #pragma unroll
    for (int j = 0; j < 7; ++j) out[r * 7 + j] = acc[j];
}

extern "C" void kernel_launch(void* const* d_in, const int* in_sizes, int n_in,
                              void* d_out, int out_size, void* d_ws, size_t ws_size,
                              hipStream_t stream) {
    const int*   frame = (const int*)d_in[0];
    const int*   ccol  = (const int*)d_in[1];
    const int*   cobj  = (const int*)d_in[2];
    const float* w1    = (const float*)d_in[3];
    const float* b1    = (const float*)d_in[4];
    const float* w2    = (const float*)d_in[5];
    const float* b2    = (const float*)d_in[6];
    const float* w3    = (const float*)d_in[7];
    const float* b3    = (const float*)d_in[8];
    const float* pw    = (const float*)d_in[9];
    const float* pb    = (const float*)d_in[10];
    const float* h1w   = (const float*)d_in[11];
    const float* h1b   = (const float*)d_in[12];
    const float* lng   = (const float*)d_in[13];
    const float* lnb   = (const float*)d_in[14];
    const float* h2w   = (const float*)d_in[15];
    const float* h2b   = (const float*)d_in[16];
    const float* h3w   = (const float*)d_in[17];
    const float* h3b   = (const float*)d_in[18];
    float* out = (float*)d_out;

    char* ws = (char*)d_ws;
    // Region A [0,32MB): pooled1b (k1->k2); then emb fp32 (k4) + extras (k5)
    // Region B [32MB,48MB): pooled2 (k2->k3); then h1out fp32 (k6b->k7)
    // Region C [48MB,124.5MB): feat (k3->k4); then h2out (48..64, k7->k8),
    //          comb (70..91, k5b->k6a), h1pre (91..107, k6a->k6b)
    // Region D [126MB+): converted weights (k0 -> consumers)
    u16*   pooled1b = (u16*)(ws + 0);                    // 32 MB
    float* emb      = (float*)(ws + 0);                  // 16 MB (after k2)
    float* extras   = (float*)(ws + 16777216);           // 512 KB
    u16*   pooled2  = (u16*)(ws + 33554432);             // 16 MB
    float* h1out    = (float*)(ws + 33554432);           // 16 MB (after k3)
    u16*   feat     = (u16*)(ws + 50331648);             // 76.5 MB
    float* h2out    = (float*)(ws + 50331648);           // 16 MB (after k4)
    float* comb     = (float*)(ws + 73400320);           // 21 MB (after k4)
    float* h1pre    = (float*)(ws + 95420416);           // 16 MB (after k4)
    u16*   pwT      = (u16*)(ws + 132120576);            // 77824 B
    u16*   w2r      = (u16*)(ws + 132120576 + 131072);   // 4096 B
    u16*   w3r      = (u16*)(ws + 132120576 + 139264);   // 16384 B
    u16*   h2hi     = (u16*)(ws + 132120576 + 163840);   // 32768 B
    u16*   h2lo     = (u16*)(ws + 132120576 + 196608);   // 32768 B
    u16*   h1hi     = (u16*)(ws + 132120576 + 229376);   // 40960 B
    u16*   h1lo     = (u16*)(ws + 132120576 + 270336);   // 40960 B

    k0_prep<<<336, 256, 0, stream>>>(pw, w2, w3, h2w, h1w,
                                     pwT, w2r, w3r, h2hi, h2lo, h1hi, h1lo);
    k1_conv1<<<4096, 256, 0, stream>>>(frame, w1, b1, pooled1b);
    k2_conv2_mfma<<<1024, 256, 0, stream>>>(pooled1b, w2r, b2, pooled2);
    k3_conv3_mfma<<<1024, 256, 0, stream>>>(pooled2, w3r, b3, feat);
    k3_tail<<<256, 256, 0, stream>>>(ccol, cobj, feat);
    k4_proj_mfma<<<1024, 256, 0, stream>>>(feat, pwT, pb, emb);
    k5_extras<<<128, 256, 0, stream>>>(frame, extras);
    k5b_pack<<<4096, 256, 0, stream>>>(emb, extras, comb);
    k6_h1_gemm<<<512, 256, 0, stream>>>(comb, h1hi, h1lo, h1b, h1pre);
    k6_ln<<<8192, 256, 0, stream>>>(h1pre, lng, lnb, h1out);
    k7_h2_mfma<<<512, 256, 0, stream>>>(h1out, h2hi, h2lo, h2b, h2out);
    k8_h3<<<128, 256, 0, stream>>>(h2out, h3w, h3b, out);
}